// Round 6
// baseline (739.421 us; speedup 1.0000x reference)
//
#include <hip/hip_runtime.h>

#define DD 64

// ---------------- CSR build: counting-sort by src, then by dst ----------------

// histogram both endpoints in one pass
__global__ __launch_bounds__(256) void hist2_kernel(
    const int* __restrict__ ei, int* __restrict__ src_cnt,
    int* __restrict__ dst_cnt, int E)
{
    int e = blockIdx.x * 256 + threadIdx.x;
    if (e < E) {
        atomicAdd(&src_cnt[ei[e]], 1);
        atomicAdd(&dst_cnt[ei[E + e]], 1);
    }
}

// per-256-tile sums
__global__ __launch_bounds__(256) void scanA_kernel(
    const int* __restrict__ cnt, int* __restrict__ bsum, int N)
{
    __shared__ int s[256];
    int idx = blockIdx.x * 256 + threadIdx.x;
    s[threadIdx.x] = (idx < N) ? cnt[idx] : 0;
    __syncthreads();
    for (int off = 128; off > 0; off >>= 1) {
        if (threadIdx.x < off) s[threadIdx.x] += s[threadIdx.x + off];
        __syncthreads();
    }
    if (threadIdx.x == 0) bsum[blockIdx.x] = s[0];
}

// exclusive scan of bsum[nb] in place; single block, any nb
__global__ __launch_bounds__(256) void scanB_kernel(int* __restrict__ bsum, int nb)
{
    __shared__ int s[256];
    int carry = 0;
    for (int base = 0; base < nb; base += 256) {
        int i = base + threadIdx.x;
        int v = (i < nb) ? bsum[i] : 0;
        s[threadIdx.x] = v;
        __syncthreads();
        for (int off = 1; off < 256; off <<= 1) {
            int t = (threadIdx.x >= off) ? s[threadIdx.x - off] : 0;
            __syncthreads();
            s[threadIdx.x] += t;
            __syncthreads();
        }
        if (i < nb) bsum[i] = carry + s[threadIdx.x] - v;   // exclusive
        int tot = s[255];
        __syncthreads();
        carry += tot;
    }
}

__global__ __launch_bounds__(256) void scanC_kernel(
    const int* __restrict__ cnt, const int* __restrict__ bsum,
    int* __restrict__ ptr, int N, int E)
{
    __shared__ int s[256];
    int idx = blockIdx.x * 256 + threadIdx.x;
    int v = (idx < N) ? cnt[idx] : 0;
    s[threadIdx.x] = v;
    __syncthreads();
    for (int off = 1; off < 256; off <<= 1) {
        int t = (threadIdx.x >= off) ? s[threadIdx.x - off] : 0;
        __syncthreads();
        s[threadIdx.x] += t;
        __syncthreads();
    }
    if (idx < N) ptr[idx] = s[threadIdx.x] - v + bsum[blockIdx.x];
    if (idx == N) ptr[N] = E;
}

// pass A: scatter edges into src-sorted order. src_ptr is consumed as cursor.
__global__ __launch_bounds__(256) void fillA_kernel(
    const int* __restrict__ ei, const float* __restrict__ ew,
    int* __restrict__ src_cursor, float2* __restrict__ tmp_dw,
    int* __restrict__ tmp_src, int E)
{
    int e = blockIdx.x * 256 + threadIdx.x;
    if (e >= E) return;
    int s = ei[e];
    int d = ei[E + e];
    int pos = atomicAdd(&src_cursor[s], 1);
    tmp_dw[pos] = make_float2(__int_as_float(d), ew[e]);
    tmp_src[pos] = s;
}

// pass B: place into dst-CSR processing edges in src-sorted order, so each
// row receives its edges approximately sorted by src (locality for gather).
__global__ __launch_bounds__(256) void fillB_kernel(
    const float2* __restrict__ tmp_dw, const int* __restrict__ tmp_src,
    int* __restrict__ dst_cursor, float2* __restrict__ edges, int E)
{
    int t = blockIdx.x * 256 + threadIdx.x;
    if (t >= E) return;
    float2 dw = tmp_dw[t];
    int d = __float_as_int(dw.x);
    int pos = atomicAdd(&dst_cursor[d], 1);
    edges[pos] = make_float2(__int_as_float(tmp_src[t]), dw.y);
}

// ---------------- compute kernels ----------------

// out[n][c] = bias[c] + sum_d T[n][d]*W[d][c]   (T_0 term)
__global__ __launch_bounds__(256) void gemm_init_kernel(
    const float* __restrict__ T, const float* __restrict__ W,
    const float* __restrict__ bias, float* __restrict__ out, int N)
{
    __shared__ float Ws[DD * DD];
    for (int i = threadIdx.x; i < DD * DD; i += 256) Ws[i] = W[i];
    __syncthreads();
    int n = blockIdx.x * 4 + (threadIdx.x >> 6);
    int c = threadIdx.x & 63;
    if (n >= N) return;
    float tr = T[(size_t)n * DD + c];
    float acc = bias[c];
#pragma unroll
    for (int d = 0; d < DD; ++d)
        acc = fmaf(__shfl(tr, d), Ws[d * DD + c], acc);
    out[(size_t)n * DD + c] = acc;
}

// Fused propagate + recurrence + GEMM accumulate. One 64-lane wave per node,
// 4 waves/block. 8 groups x 8 lanes; each group gathers one edge's 256B row,
// each lane covering 8 channels via two float4 loads (16 edges/iter).
// Cross-group xor-shuffle reduce (masks 8/16/32), then t = 2*t - prev,
// Tnext = t (group 0 writes), out += t @ Wk (LDS W, shfl row-broadcast).
// ALIASING CONTRACT: Tnext may alias prev; must NOT alias h.
__global__ __launch_bounds__(256) void prop_fused_kernel(
    const float* __restrict__ h, const float* __restrict__ prev,
    const float2* __restrict__ edges, const int* __restrict__ row_ptr,
    const float* __restrict__ Wk, float* __restrict__ out,
    float* __restrict__ Tnext, int N)
{
    __shared__ float Ws[DD * DD];
    for (int i = threadIdx.x; i < DD * DD; i += 256) Ws[i] = Wk[i];
    __syncthreads();

    int lane = threadIdx.x & 63;
    int n = blockIdx.x * 4 + (threadIdx.x >> 6);
    if (n >= N) return;

    int g  = lane >> 3;        // edge group 0..7
    int c8 = (lane & 7) << 3;  // channel base: 8 channels per lane

    int beg = row_ptr[n], end = row_ptr[n + 1];

    float4 acc0 = make_float4(0.f, 0.f, 0.f, 0.f);
    float4 acc1 = make_float4(0.f, 0.f, 0.f, 0.f);
    const float2 zed = make_float2(__int_as_float(0), 0.f);

    for (int base = beg; base < end; base += 16) {
        int ea = base + g;
        int eb = base + 8 + g;
        float2 EA = (ea < end) ? edges[ea] : zed;
        float2 EB = (eb < end) ? edges[eb] : zed;
        const float* ra = &h[(size_t)__float_as_int(EA.x) * DD + c8];
        const float* rb = &h[(size_t)__float_as_int(EB.x) * DD + c8];
        float4 va0 = *reinterpret_cast<const float4*>(ra);
        float4 va1 = *reinterpret_cast<const float4*>(ra + 4);
        float4 vb0 = *reinterpret_cast<const float4*>(rb);
        float4 vb1 = *reinterpret_cast<const float4*>(rb + 4);
        acc0.x = fmaf(EA.y, va0.x, acc0.x);
        acc0.y = fmaf(EA.y, va0.y, acc0.y);
        acc0.z = fmaf(EA.y, va0.z, acc0.z);
        acc0.w = fmaf(EA.y, va0.w, acc0.w);
        acc1.x = fmaf(EA.y, va1.x, acc1.x);
        acc1.y = fmaf(EA.y, va1.y, acc1.y);
        acc1.z = fmaf(EA.y, va1.z, acc1.z);
        acc1.w = fmaf(EA.y, va1.w, acc1.w);
        acc0.x = fmaf(EB.y, vb0.x, acc0.x);
        acc0.y = fmaf(EB.y, vb0.y, acc0.y);
        acc0.z = fmaf(EB.y, vb0.z, acc0.z);
        acc0.w = fmaf(EB.y, vb0.w, acc0.w);
        acc1.x = fmaf(EB.y, vb1.x, acc1.x);
        acc1.y = fmaf(EB.y, vb1.y, acc1.y);
        acc1.z = fmaf(EB.y, vb1.z, acc1.z);
        acc1.w = fmaf(EB.y, vb1.w, acc1.w);
    }

    // reduce partials across the 8 groups (lane bits 3,4,5)
#pragma unroll
    for (int m = 8; m <= 32; m <<= 1) {
        acc0.x += __shfl_xor(acc0.x, m);
        acc0.y += __shfl_xor(acc0.y, m);
        acc0.z += __shfl_xor(acc0.z, m);
        acc0.w += __shfl_xor(acc0.w, m);
        acc1.x += __shfl_xor(acc1.x, m);
        acc1.y += __shfl_xor(acc1.y, m);
        acc1.z += __shfl_xor(acc1.z, m);
        acc1.w += __shfl_xor(acc1.w, m);
    }

    if (prev) {
        const float4 p0 = *reinterpret_cast<const float4*>(&prev[(size_t)n * DD + c8]);
        const float4 p1 = *reinterpret_cast<const float4*>(&prev[(size_t)n * DD + c8 + 4]);
        acc0.x = 2.f * acc0.x - p0.x;
        acc0.y = 2.f * acc0.y - p0.y;
        acc0.z = 2.f * acc0.z - p0.z;
        acc0.w = 2.f * acc0.w - p0.w;
        acc1.x = 2.f * acc1.x - p1.x;
        acc1.y = 2.f * acc1.y - p1.y;
        acc1.z = 2.f * acc1.z - p1.z;
        acc1.w = 2.f * acc1.w - p1.w;
    }
    if (g == 0) {
        *reinterpret_cast<float4*>(&Tnext[(size_t)n * DD + c8]) = acc0;
        *reinterpret_cast<float4*>(&Tnext[(size_t)n * DD + c8 + 4]) = acc1;
    }

    // out[n][lane] += sum_d T[n][d] * Wk[d][lane]
    float o = out[(size_t)n * DD + lane];
#pragma unroll
    for (int sl = 0; sl < 8; ++sl) {
        float t0 = __shfl(acc0.x, sl);
        float t1 = __shfl(acc0.y, sl);
        float t2 = __shfl(acc0.z, sl);
        float t3 = __shfl(acc0.w, sl);
        float t4 = __shfl(acc1.x, sl);
        float t5 = __shfl(acc1.y, sl);
        float t6 = __shfl(acc1.z, sl);
        float t7 = __shfl(acc1.w, sl);
        o = fmaf(t0, Ws[(8 * sl + 0) * DD + lane], o);
        o = fmaf(t1, Ws[(8 * sl + 1) * DD + lane], o);
        o = fmaf(t2, Ws[(8 * sl + 2) * DD + lane], o);
        o = fmaf(t3, Ws[(8 * sl + 3) * DD + lane], o);
        o = fmaf(t4, Ws[(8 * sl + 4) * DD + lane], o);
        o = fmaf(t5, Ws[(8 * sl + 5) * DD + lane], o);
        o = fmaf(t6, Ws[(8 * sl + 6) * DD + lane], o);
        o = fmaf(t7, Ws[(8 * sl + 7) * DD + lane], o);
    }
    out[(size_t)n * DD + lane] = o;
}

// ---------------- launch ----------------

static inline size_t rup(size_t x) { return (x + 255) & ~(size_t)255; }

extern "C" void kernel_launch(void* const* d_in, const int* in_sizes, int n_in,
                              void* d_out, int out_size, void* d_ws, size_t ws_size,
                              hipStream_t stream) {
    const float* x    = (const float*)d_in[0];
    const int*   ei   = (const int*)  d_in[1];
    const float* ew   = (const float*)d_in[2];
    const float* W    = (const float*)d_in[3];
    const float* bias = (const float*)d_in[4];
    float* out = (float*)d_out;

    int N = in_sizes[0] / DD;
    int E = in_sizes[2];
    int K = in_sizes[3] / (DD * DD);

    size_t nb = (size_t)N * DD * sizeof(float);
    int nb_scan = (N + 1 + 255) / 256;

    char* w = (char*)d_ws;
    float*  bufA    = (float*)w;            w += rup(nb);
    float*  bufB    = (float*)w;            w += rup(nb);
    float2* edges   = (float2*)w;           w += rup((size_t)E * sizeof(float2));
    int*    cnt     = (int*)w;              w += rup((size_t)N * sizeof(int));      // dst hist -> cursor
    int*    row_ptr = (int*)w;              w += rup((size_t)(N + 1) * sizeof(int));
    int*    bsum    = (int*)w;              w += rup((size_t)nb_scan * sizeof(int));
    int*    src_cnt = (int*)w;              w += rup((size_t)N * sizeof(int));
    int*    src_ptr = (int*)w;              w += rup((size_t)(N + 1) * sizeof(int)); // consumed as cursor

    // build-time temporaries alias the T ping-pong buffers (dead during build)
    float2* tmp_dw  = (float2*)bufA;        // E * 8B  <= nb
    int*    tmp_src = (int*)bufB;           // E * 4B  <= nb

    int eb = (E + 255) / 256;
    int gb = (N + 3) / 4;

    // ---- CSR build with src-sorted rows ----
    hipMemsetAsync(cnt, 0, (size_t)N * sizeof(int), stream);
    hipMemsetAsync(src_cnt, 0, (size_t)N * sizeof(int), stream);
    hist2_kernel<<<eb, 256, 0, stream>>>(ei, src_cnt, cnt, E);

    // src exclusive scan -> src_ptr
    scanA_kernel<<<nb_scan, 256, 0, stream>>>(src_cnt, bsum, N);
    scanB_kernel<<<1, 256, 0, stream>>>(bsum, nb_scan);
    scanC_kernel<<<nb_scan, 256, 0, stream>>>(src_cnt, bsum, src_ptr, N, E);
    // pass A: src-sorted order (src_ptr destroyed as cursor; unused after)
    fillA_kernel<<<eb, 256, 0, stream>>>(ei, ew, src_ptr, tmp_dw, tmp_src, E);

    // dst exclusive scan -> row_ptr
    scanA_kernel<<<nb_scan, 256, 0, stream>>>(cnt, bsum, N);
    scanB_kernel<<<1, 256, 0, stream>>>(bsum, nb_scan);
    scanC_kernel<<<nb_scan, 256, 0, stream>>>(cnt, bsum, row_ptr, N, E);
    hipMemcpyAsync(cnt, row_ptr, (size_t)N * sizeof(int),
                   hipMemcpyDeviceToDevice, stream);           // cnt -> cursor
    // pass B: place into dst-CSR in src-sorted processing order
    fillB_kernel<<<eb, 256, 0, stream>>>(tmp_dw, tmp_src, cnt, edges, E);

    // ---- T_0 term ----
    gemm_init_kernel<<<gb, 256, 0, stream>>>(x, W, bias, out, N);

    if (K > 1) {
        // T_1 = prop(x); out += T_1 @ W_1   (bufA safe to reuse now)
        prop_fused_kernel<<<gb, 256, 0, stream>>>(
            x, nullptr, edges, row_ptr, W + DD * DD, out, bufA, N);
    }

    // T_k = 2*prop(T_{k-1}) - T_{k-2}; out += T_k @ W_k
    // Rotation (2 buffers):
    //   k=2: prop(bufA, x    -> bufB)
    //   k=3: prop(bufB, bufA -> bufA)   (Tnext aliases prev: safe)
    //   k=4: prop(bufA, bufB -> bufB)   ... alternating
    const float* prev = x;
    float*       cur  = bufA;
    float*       nxt  = bufB;
    for (int k = 2; k < K; ++k) {
        prop_fused_kernel<<<gb, 256, 0, stream>>>(
            cur, prev, edges, row_ptr, W + (size_t)k * DD * DD, out, nxt, N);
        float* old_cur = cur;
        cur  = nxt;          // T_k becomes current
        prev = old_cur;      // T_{k-1} becomes previous
        nxt  = old_cur;      // write T_{k+1} over dead T_{k-1} (alias prev: safe)
    }
}

// Round 7
// 652.687 us; speedup vs baseline: 1.1329x; 1.1329x over previous
//
#include <hip/hip_runtime.h>

#define DD 64

// ---------------- bf16 helpers (RTN-even) ----------------

__device__ __forceinline__ unsigned pk_bf16(float a, float b) {
    unsigned ua = __float_as_uint(a), ub = __float_as_uint(b);
    ua = (ua + 0x7fffu + ((ua >> 16) & 1u)) >> 16;          // low half
    ub = (ub + 0x7fffu + ((ub >> 16) & 1u)) & 0xffff0000u;  // high half
    return (ua & 0xffffu) | ub;
}
__device__ __forceinline__ void unpk_bf16(unsigned u, float& lo, float& hi) {
    lo = __uint_as_float(u << 16);
    hi = __uint_as_float(u & 0xffff0000u);
}

// ---------------- CSR build (by destination) ----------------

__global__ __launch_bounds__(256) void hist_kernel(
    const int* __restrict__ ei, int* __restrict__ cnt, int E)
{
    int e = blockIdx.x * 256 + threadIdx.x;
    if (e < E) atomicAdd(&cnt[ei[E + e]], 1);
}

__global__ __launch_bounds__(256) void scanA_kernel(
    const int* __restrict__ cnt, int* __restrict__ bsum, int N)
{
    __shared__ int s[256];
    int idx = blockIdx.x * 256 + threadIdx.x;
    s[threadIdx.x] = (idx < N) ? cnt[idx] : 0;
    __syncthreads();
    for (int off = 128; off > 0; off >>= 1) {
        if (threadIdx.x < off) s[threadIdx.x] += s[threadIdx.x + off];
        __syncthreads();
    }
    if (threadIdx.x == 0) bsum[blockIdx.x] = s[0];
}

__global__ __launch_bounds__(256) void scanB_kernel(int* __restrict__ bsum, int nb)
{
    __shared__ int s[256];
    int carry = 0;
    for (int base = 0; base < nb; base += 256) {
        int i = base + threadIdx.x;
        int v = (i < nb) ? bsum[i] : 0;
        s[threadIdx.x] = v;
        __syncthreads();
        for (int off = 1; off < 256; off <<= 1) {
            int t = (threadIdx.x >= off) ? s[threadIdx.x - off] : 0;
            __syncthreads();
            s[threadIdx.x] += t;
            __syncthreads();
        }
        if (i < nb) bsum[i] = carry + s[threadIdx.x] - v;   // exclusive
        int tot = s[255];
        __syncthreads();
        carry += tot;
    }
}

__global__ __launch_bounds__(256) void scanC_kernel(
    const int* __restrict__ cnt, const int* __restrict__ bsum,
    int* __restrict__ row_ptr, int N, int E)
{
    __shared__ int s[256];
    int idx = blockIdx.x * 256 + threadIdx.x;
    int v = (idx < N) ? cnt[idx] : 0;
    s[threadIdx.x] = v;
    __syncthreads();
    for (int off = 1; off < 256; off <<= 1) {
        int t = (threadIdx.x >= off) ? s[threadIdx.x - off] : 0;
        __syncthreads();
        s[threadIdx.x] += t;
        __syncthreads();
    }
    if (idx < N) row_ptr[idx] = s[threadIdx.x] - v + bsum[blockIdx.x];
    if (idx == N) row_ptr[N] = E;
}

__global__ __launch_bounds__(256) void fill_kernel(
    const int* __restrict__ ei, const float* __restrict__ ew,
    int* __restrict__ cursor, float2* __restrict__ edges, int E)
{
    int e = blockIdx.x * 256 + threadIdx.x;
    if (e >= E) return;
    int dst = ei[E + e];
    int pos = atomicAdd(&cursor[dst], 1);
    edges[pos] = make_float2(__int_as_float(ei[e]), ew[e]);
}

// quantize fp32 -> packed bf16 (8 elems / thread)
__global__ __launch_bounds__(256) void quant_kernel(
    const float4* __restrict__ src, uint4* __restrict__ dst, int n8)
{
    int i = blockIdx.x * 256 + threadIdx.x;
    if (i >= n8) return;
    float4 a = src[2 * i], b = src[2 * i + 1];
    dst[i] = make_uint4(pk_bf16(a.x, a.y), pk_bf16(a.z, a.w),
                        pk_bf16(b.x, b.y), pk_bf16(b.z, b.w));
}

// ---------------- compute kernels ----------------

// out[n][c] = bias[c] + sum_d T[n][d]*W[d][c]   (T_0 term, fp32 x)
__global__ __launch_bounds__(256) void gemm_init_kernel(
    const float* __restrict__ T, const float* __restrict__ W,
    const float* __restrict__ bias, float* __restrict__ out, int N)
{
    __shared__ float Ws[DD * DD];
    for (int i = threadIdx.x; i < DD * DD; i += 256) Ws[i] = W[i];
    __syncthreads();
    int n = blockIdx.x * 4 + (threadIdx.x >> 6);
    int c = threadIdx.x & 63;
    if (n >= N) return;
    float tr = T[(size_t)n * DD + c];
    float acc = bias[c];
#pragma unroll
    for (int d = 0; d < DD; ++d)
        acc = fmaf(__shfl(tr, d), Ws[d * DD + c], acc);
    out[(size_t)n * DD + c] = acc;
}

// Fused propagate + recurrence + GEMM accumulate, bf16 T-storage.
// One 64-lane wave per node, 4 waves/block. 8 groups x 8 lanes; each group
// gathers one edge's 128B bf16 row, each lane one uint4 (8 bf16 channels).
// 16 edges/iter, fp32 accumulate. Cross-group xor-shuffle reduce, then
// t = 2*t - prev(bf16), Tnext(bf16) = t (group 0), out(fp32) += t @ Wk.
// ALIASING CONTRACT: Tnext may alias prev; must NOT alias h.
__global__ __launch_bounds__(256) void prop_fused_kernel(
    const unsigned short* __restrict__ h, const unsigned short* __restrict__ prev,
    const float2* __restrict__ edges, const int* __restrict__ row_ptr,
    const float* __restrict__ Wk, float* __restrict__ out,
    unsigned short* __restrict__ Tnext, int N)
{
    __shared__ float Ws[DD * DD];
    for (int i = threadIdx.x; i < DD * DD; i += 256) Ws[i] = Wk[i];
    __syncthreads();

    int lane = threadIdx.x & 63;
    int n = blockIdx.x * 4 + (threadIdx.x >> 6);
    if (n >= N) return;

    int g  = lane >> 3;        // edge group 0..7
    int c8 = (lane & 7) << 3;  // channel base: 8 bf16 channels per lane

    int beg = row_ptr[n], end = row_ptr[n + 1];

    float4 acc0 = make_float4(0.f, 0.f, 0.f, 0.f);
    float4 acc1 = make_float4(0.f, 0.f, 0.f, 0.f);
    const float2 zed = make_float2(__int_as_float(0), 0.f);

    for (int base = beg; base < end; base += 16) {
        int ea = base + g;
        int eb = base + 8 + g;
        float2 EA = (ea < end) ? edges[ea] : zed;
        float2 EB = (eb < end) ? edges[eb] : zed;
        const uint4 va = *reinterpret_cast<const uint4*>(
            &h[(size_t)__float_as_int(EA.x) * DD + c8]);
        const uint4 vb = *reinterpret_cast<const uint4*>(
            &h[(size_t)__float_as_int(EB.x) * DD + c8]);
        float lo, hi;
        unpk_bf16(va.x, lo, hi);
        acc0.x = fmaf(EA.y, lo, acc0.x); acc0.y = fmaf(EA.y, hi, acc0.y);
        unpk_bf16(va.y, lo, hi);
        acc0.z = fmaf(EA.y, lo, acc0.z); acc0.w = fmaf(EA.y, hi, acc0.w);
        unpk_bf16(va.z, lo, hi);
        acc1.x = fmaf(EA.y, lo, acc1.x); acc1.y = fmaf(EA.y, hi, acc1.y);
        unpk_bf16(va.w, lo, hi);
        acc1.z = fmaf(EA.y, lo, acc1.z); acc1.w = fmaf(EA.y, hi, acc1.w);
        unpk_bf16(vb.x, lo, hi);
        acc0.x = fmaf(EB.y, lo, acc0.x); acc0.y = fmaf(EB.y, hi, acc0.y);
        unpk_bf16(vb.y, lo, hi);
        acc0.z = fmaf(EB.y, lo, acc0.z); acc0.w = fmaf(EB.y, hi, acc0.w);
        unpk_bf16(vb.z, lo, hi);
        acc1.x = fmaf(EB.y, lo, acc1.x); acc1.y = fmaf(EB.y, hi, acc1.y);
        unpk_bf16(vb.w, lo, hi);
        acc1.z = fmaf(EB.y, lo, acc1.z); acc1.w = fmaf(EB.y, hi, acc1.w);
    }

    // reduce partials across the 8 groups (lane bits 3,4,5)
#pragma unroll
    for (int m = 8; m <= 32; m <<= 1) {
        acc0.x += __shfl_xor(acc0.x, m);
        acc0.y += __shfl_xor(acc0.y, m);
        acc0.z += __shfl_xor(acc0.z, m);
        acc0.w += __shfl_xor(acc0.w, m);
        acc1.x += __shfl_xor(acc1.x, m);
        acc1.y += __shfl_xor(acc1.y, m);
        acc1.z += __shfl_xor(acc1.z, m);
        acc1.w += __shfl_xor(acc1.w, m);
    }

    if (prev) {
        const uint4 p = *reinterpret_cast<const uint4*>(&prev[(size_t)n * DD + c8]);
        float lo, hi;
        unpk_bf16(p.x, lo, hi);
        acc0.x = 2.f * acc0.x - lo; acc0.y = 2.f * acc0.y - hi;
        unpk_bf16(p.y, lo, hi);
        acc0.z = 2.f * acc0.z - lo; acc0.w = 2.f * acc0.w - hi;
        unpk_bf16(p.z, lo, hi);
        acc1.x = 2.f * acc1.x - lo; acc1.y = 2.f * acc1.y - hi;
        unpk_bf16(p.w, lo, hi);
        acc1.z = 2.f * acc1.z - lo; acc1.w = 2.f * acc1.w - hi;
    }
    if (g == 0) {
        *reinterpret_cast<uint4*>(&Tnext[(size_t)n * DD + c8]) =
            make_uint4(pk_bf16(acc0.x, acc0.y), pk_bf16(acc0.z, acc0.w),
                       pk_bf16(acc1.x, acc1.y), pk_bf16(acc1.z, acc1.w));
    }

    // out[n][lane] += sum_d T[n][d] * Wk[d][lane]
    // value for d = sl*8+j lives in lane sl, reg j
    float o = out[(size_t)n * DD + lane];
#pragma unroll
    for (int sl = 0; sl < 8; ++sl) {
        float t0 = __shfl(acc0.x, sl);
        float t1 = __shfl(acc0.y, sl);
        float t2 = __shfl(acc0.z, sl);
        float t3 = __shfl(acc0.w, sl);
        float t4 = __shfl(acc1.x, sl);
        float t5 = __shfl(acc1.y, sl);
        float t6 = __shfl(acc1.z, sl);
        float t7 = __shfl(acc1.w, sl);
        o = fmaf(t0, Ws[(8 * sl + 0) * DD + lane], o);
        o = fmaf(t1, Ws[(8 * sl + 1) * DD + lane], o);
        o = fmaf(t2, Ws[(8 * sl + 2) * DD + lane], o);
        o = fmaf(t3, Ws[(8 * sl + 3) * DD + lane], o);
        o = fmaf(t4, Ws[(8 * sl + 4) * DD + lane], o);
        o = fmaf(t5, Ws[(8 * sl + 5) * DD + lane], o);
        o = fmaf(t6, Ws[(8 * sl + 6) * DD + lane], o);
        o = fmaf(t7, Ws[(8 * sl + 7) * DD + lane], o);
    }
    out[(size_t)n * DD + lane] = o;
}

// ---------------- launch ----------------

static inline size_t rup(size_t x) { return (x + 255) & ~(size_t)255; }

extern "C" void kernel_launch(void* const* d_in, const int* in_sizes, int n_in,
                              void* d_out, int out_size, void* d_ws, size_t ws_size,
                              hipStream_t stream) {
    const float* x    = (const float*)d_in[0];
    const int*   ei   = (const int*)  d_in[1];
    const float* ew   = (const float*)d_in[2];
    const float* W    = (const float*)d_in[3];
    const float* bias = (const float*)d_in[4];
    float* out = (float*)d_out;

    int N = in_sizes[0] / DD;
    int E = in_sizes[2];
    int K = in_sizes[3] / (DD * DD);

    size_t nb_bf = (size_t)N * DD * sizeof(unsigned short);  // bf16 T buffer
    int nb_scan = (N + 1 + 255) / 256;

    char* w = (char*)d_ws;
    unsigned short* xq   = (unsigned short*)w;  w += rup(nb_bf);
    unsigned short* bufA = (unsigned short*)w;  w += rup(nb_bf);
    unsigned short* bufB = (unsigned short*)w;  w += rup(nb_bf);
    float2* edges   = (float2*)w;               w += rup((size_t)E * sizeof(float2));
    int*    cnt     = (int*)w;                  w += rup((size_t)N * sizeof(int));
    int*    row_ptr = (int*)w;                  w += rup((size_t)(N + 1) * sizeof(int));
    int*    bsum    = (int*)w;                  w += rup((size_t)nb_scan * sizeof(int));

    int eb = (E + 255) / 256;
    int gb = (N + 3) / 4;
    int n8 = (N * DD) / 8;
    int qb = (n8 + 255) / 256;

    // ---- CSR build ----
    hipMemsetAsync(cnt, 0, (size_t)N * sizeof(int), stream);
    hist_kernel<<<eb, 256, 0, stream>>>(ei, cnt, E);
    scanA_kernel<<<nb_scan, 256, 0, stream>>>(cnt, bsum, N);
    scanB_kernel<<<1, 256, 0, stream>>>(bsum, nb_scan);
    scanC_kernel<<<nb_scan, 256, 0, stream>>>(cnt, bsum, row_ptr, N, E);
    hipMemcpyAsync(cnt, row_ptr, (size_t)N * sizeof(int),
                   hipMemcpyDeviceToDevice, stream);           // cnt -> cursor
    fill_kernel<<<eb, 256, 0, stream>>>(ei, ew, cnt, edges, E);

    // ---- quantize x for gathering ----
    quant_kernel<<<qb, 256, 0, stream>>>((const float4*)x, (uint4*)xq, n8);

    // ---- T_0 term (fp32 x) ----
    gemm_init_kernel<<<gb, 256, 0, stream>>>(x, W, bias, out, N);

    if (K > 1) {
        // T_1 = prop(x); out += T_1 @ W_1
        prop_fused_kernel<<<gb, 256, 0, stream>>>(
            xq, nullptr, edges, row_ptr, W + DD * DD, out, bufA, N);
    }

    // T_k = 2*prop(T_{k-1}) - T_{k-2}; out += T_k @ W_k
    // Rotation (bf16 buffers):
    //   k=2: prop(bufA, xq   -> bufB)
    //   k=3: prop(bufB, bufA -> bufA)   (Tnext aliases prev: safe)
    //   k=4: prop(bufA, bufB -> bufB)   ... alternating
    const unsigned short* prev = xq;
    unsigned short*       cur  = bufA;
    unsigned short*       nxt  = bufB;
    for (int k = 2; k < K; ++k) {
        prop_fused_kernel<<<gb, 256, 0, stream>>>(
            cur, prev, edges, row_ptr, W + (size_t)k * DD * DD, out, nxt, N);
        unsigned short* old_cur = cur;
        cur  = nxt;
        prev = old_cur;
        nxt  = old_cur;
    }
}

// Round 8
// 492.615 us; speedup vs baseline: 1.5010x; 1.3249x over previous
//
#include <hip/hip_runtime.h>

#define DD 64

// ---------------- bf16 helpers (RTN-even) ----------------

__device__ __forceinline__ unsigned pk_bf16(float a, float b) {
    unsigned ua = __float_as_uint(a), ub = __float_as_uint(b);
    ua = (ua + 0x7fffu + ((ua >> 16) & 1u)) >> 16;          // low half
    ub = (ub + 0x7fffu + ((ub >> 16) & 1u)) & 0xffff0000u;  // high half
    return (ua & 0xffffu) | ub;
}
__device__ __forceinline__ void unpk_bf16(unsigned u, float& lo, float& hi) {
    lo = __uint_as_float(u << 16);
    hi = __uint_as_float(u & 0xffff0000u);
}

// ---------------- CSR build (by destination) ----------------

__global__ __launch_bounds__(256) void hist_kernel(
    const int* __restrict__ ei, int* __restrict__ cnt, int E)
{
    int e = blockIdx.x * 256 + threadIdx.x;
    if (e < E) atomicAdd(&cnt[ei[E + e]], 1);
}

__global__ __launch_bounds__(256) void scanA_kernel(
    const int* __restrict__ cnt, int* __restrict__ bsum, int N)
{
    __shared__ int s[256];
    int idx = blockIdx.x * 256 + threadIdx.x;
    s[threadIdx.x] = (idx < N) ? cnt[idx] : 0;
    __syncthreads();
    for (int off = 128; off > 0; off >>= 1) {
        if (threadIdx.x < off) s[threadIdx.x] += s[threadIdx.x + off];
        __syncthreads();
    }
    if (threadIdx.x == 0) bsum[blockIdx.x] = s[0];
}

__global__ __launch_bounds__(256) void scanB_kernel(int* __restrict__ bsum, int nb)
{
    __shared__ int s[256];
    int carry = 0;
    for (int base = 0; base < nb; base += 256) {
        int i = base + threadIdx.x;
        int v = (i < nb) ? bsum[i] : 0;
        s[threadIdx.x] = v;
        __syncthreads();
        for (int off = 1; off < 256; off <<= 1) {
            int t = (threadIdx.x >= off) ? s[threadIdx.x - off] : 0;
            __syncthreads();
            s[threadIdx.x] += t;
            __syncthreads();
        }
        if (i < nb) bsum[i] = carry + s[threadIdx.x] - v;   // exclusive
        int tot = s[255];
        __syncthreads();
        carry += tot;
    }
}

__global__ __launch_bounds__(256) void scanC_kernel(
    const int* __restrict__ cnt, const int* __restrict__ bsum,
    int* __restrict__ row_ptr, int N, int E)
{
    __shared__ int s[256];
    int idx = blockIdx.x * 256 + threadIdx.x;
    int v = (idx < N) ? cnt[idx] : 0;
    s[threadIdx.x] = v;
    __syncthreads();
    for (int off = 1; off < 256; off <<= 1) {
        int t = (threadIdx.x >= off) ? s[threadIdx.x - off] : 0;
        __syncthreads();
        s[threadIdx.x] += t;
        __syncthreads();
    }
    if (idx < N) row_ptr[idx] = s[threadIdx.x] - v + bsum[blockIdx.x];
    if (idx == N) row_ptr[N] = E;
}

__global__ __launch_bounds__(256) void fill_kernel(
    const int* __restrict__ ei, const float* __restrict__ ew,
    int* __restrict__ cursor, float2* __restrict__ edges, int E)
{
    int e = blockIdx.x * 256 + threadIdx.x;
    if (e >= E) return;
    int dst = ei[E + e];
    int pos = atomicAdd(&cursor[dst], 1);
    edges[pos] = make_float2(__int_as_float(ei[e]), ew[e]);
}

// quantize fp32 -> packed bf16 (8 elems / thread)
__global__ __launch_bounds__(256) void quant_kernel(
    const float4* __restrict__ src, uint4* __restrict__ dst, int n8)
{
    int i = blockIdx.x * 256 + threadIdx.x;
    if (i >= n8) return;
    float4 a = src[2 * i], b = src[2 * i + 1];
    dst[i] = make_uint4(pk_bf16(a.x, a.y), pk_bf16(a.z, a.w),
                        pk_bf16(b.x, b.y), pk_bf16(b.z, b.w));
}

// ---------------- compute kernels ----------------
// Block = 256 threads = 4 waves, owns 64 nodes. Register-blocked 64x64x64
// GEMM from LDS: thread (r,c) = (tx>>4, tx&15) owns 4x4 output tile
// rows r*4+i, cols c*4+j. Per d-step: 4x ds_read_b32 (Ts) + 1x ds_read_b128
// (Ws) feed 16 FMAs  -> ~20 DS wave-instrs per node vs ~128 in the
// shuffle-broadcast scheme (the round-7 LDS-pipe bottleneck).

// out[n][c] = bias[c] + sum_d x[n][d]*W0[d][c]   (T_0 term)
__global__ __launch_bounds__(256) void gemm_init_kernel(
    const float* __restrict__ x, const float* __restrict__ W,
    const float* __restrict__ bias, float* __restrict__ out, int N)
{
    __shared__ float Ws[DD * DD];
    __shared__ float Ts[64][68];
    for (int i = threadIdx.x; i < DD * DD; i += 256) Ws[i] = W[i];

    int nb0 = blockIdx.x * 64;
    int nl = threadIdx.x >> 2;       // 0..63
    int q  = threadIdx.x & 3;        // 0..3
#pragma unroll
    for (int u = 0; u < 4; ++u) {
        int col = q * 16 + u * 4;
        float4 v = make_float4(0.f, 0.f, 0.f, 0.f);
        if (nb0 + nl < N)
            v = *reinterpret_cast<const float4*>(&x[(size_t)(nb0 + nl) * DD + col]);
        *reinterpret_cast<float4*>(&Ts[nl][col]) = v;   // 68*nl+col ≡ 0 mod 4
    }
    __syncthreads();

    int r = threadIdx.x >> 4, c = threadIdx.x & 15;
    int r4 = r * 4, c4 = c * 4;
    const float4 bb = *reinterpret_cast<const float4*>(&bias[c4]);
    float acc[4][4];
#pragma unroll
    for (int i = 0; i < 4; ++i) {
        acc[i][0] = bb.x; acc[i][1] = bb.y; acc[i][2] = bb.z; acc[i][3] = bb.w;
    }
#pragma unroll 4
    for (int d = 0; d < DD; ++d) {
        float a0 = Ts[r4 + 0][d], a1 = Ts[r4 + 1][d];
        float a2 = Ts[r4 + 2][d], a3 = Ts[r4 + 3][d];
        float4 b = *reinterpret_cast<const float4*>(&Ws[d * DD + c4]);
        acc[0][0] = fmaf(a0, b.x, acc[0][0]); acc[0][1] = fmaf(a0, b.y, acc[0][1]);
        acc[0][2] = fmaf(a0, b.z, acc[0][2]); acc[0][3] = fmaf(a0, b.w, acc[0][3]);
        acc[1][0] = fmaf(a1, b.x, acc[1][0]); acc[1][1] = fmaf(a1, b.y, acc[1][1]);
        acc[1][2] = fmaf(a1, b.z, acc[1][2]); acc[1][3] = fmaf(a1, b.w, acc[1][3]);
        acc[2][0] = fmaf(a2, b.x, acc[2][0]); acc[2][1] = fmaf(a2, b.y, acc[2][1]);
        acc[2][2] = fmaf(a2, b.z, acc[2][2]); acc[2][3] = fmaf(a2, b.w, acc[2][3]);
        acc[3][0] = fmaf(a3, b.x, acc[3][0]); acc[3][1] = fmaf(a3, b.y, acc[3][1]);
        acc[3][2] = fmaf(a3, b.z, acc[3][2]); acc[3][3] = fmaf(a3, b.w, acc[3][3]);
    }
#pragma unroll
    for (int i = 0; i < 4; ++i) {
        int n = nb0 + r4 + i;
        if (n < N) {
            float4 o = make_float4(acc[i][0], acc[i][1], acc[i][2], acc[i][3]);
            *reinterpret_cast<float4*>(&out[(size_t)n * DD + c4]) = o;
        }
    }
}

// Fused propagate + recurrence + GEMM accumulate, bf16 T-storage.
// Phase 1: wave w gathers nodes w*16..w*16+15 (8 groups x 8 lanes, bf16 rows,
// fp32 acc, xor reduce over masks 8/16/32 -> every lane holds channels
// 8j..8j+7). Recurrence vs prev (bf16), Tnext (bf16) written by g==0 lanes,
// Ts[64][68] (fp32) written with ONE ds_write_b32/node (lane (g,j) writes
// channel 8j+g; banks (4n+v)%32 2-way -> free).
// Phase 2: register-blocked GEMM as above, out += Ts @ Wk.
// ALIASING CONTRACT: Tnext may alias prev; must NOT alias h.
__global__ __launch_bounds__(256) void prop_fused_kernel(
    const unsigned short* __restrict__ h, const unsigned short* __restrict__ prev,
    const float2* __restrict__ edges, const int* __restrict__ row_ptr,
    const float* __restrict__ Wk, float* __restrict__ out,
    unsigned short* __restrict__ Tnext, int N)
{
    __shared__ float Ws[DD * DD];
    __shared__ float Ts[64][68];
    for (int i = threadIdx.x; i < DD * DD; i += 256) Ws[i] = Wk[i];

    int lane = threadIdx.x & 63;
    int wv   = threadIdx.x >> 6;
    int g  = lane >> 3;        // edge group 0..7
    int j  = lane & 7;
    int c8 = j << 3;           // channel base: 8 bf16 channels per lane
    int nb0 = blockIdx.x * 64;
    const float2 zed = make_float2(__int_as_float(0), 0.f);

    for (int m = 0; m < 16; ++m) {
        int nl = wv * 16 + m;
        int n  = nb0 + nl;
        float4 acc0 = make_float4(0.f, 0.f, 0.f, 0.f);
        float4 acc1 = make_float4(0.f, 0.f, 0.f, 0.f);

        if (n < N) {
            int beg = row_ptr[n], end = row_ptr[n + 1];
            for (int base = beg; base < end; base += 16) {
                int ea = base + g;
                int eb = base + 8 + g;
                float2 EA = (ea < end) ? edges[ea] : zed;
                float2 EB = (eb < end) ? edges[eb] : zed;
                const uint4 va = *reinterpret_cast<const uint4*>(
                    &h[(size_t)__float_as_int(EA.x) * DD + c8]);
                const uint4 vb = *reinterpret_cast<const uint4*>(
                    &h[(size_t)__float_as_int(EB.x) * DD + c8]);
                float lo, hi;
                unpk_bf16(va.x, lo, hi);
                acc0.x = fmaf(EA.y, lo, acc0.x); acc0.y = fmaf(EA.y, hi, acc0.y);
                unpk_bf16(va.y, lo, hi);
                acc0.z = fmaf(EA.y, lo, acc0.z); acc0.w = fmaf(EA.y, hi, acc0.w);
                unpk_bf16(va.z, lo, hi);
                acc1.x = fmaf(EA.y, lo, acc1.x); acc1.y = fmaf(EA.y, hi, acc1.y);
                unpk_bf16(va.w, lo, hi);
                acc1.z = fmaf(EA.y, lo, acc1.z); acc1.w = fmaf(EA.y, hi, acc1.w);
                unpk_bf16(vb.x, lo, hi);
                acc0.x = fmaf(EB.y, lo, acc0.x); acc0.y = fmaf(EB.y, hi, acc0.y);
                unpk_bf16(vb.y, lo, hi);
                acc0.z = fmaf(EB.y, lo, acc0.z); acc0.w = fmaf(EB.y, hi, acc0.w);
                unpk_bf16(vb.z, lo, hi);
                acc1.x = fmaf(EB.y, lo, acc1.x); acc1.y = fmaf(EB.y, hi, acc1.y);
                unpk_bf16(vb.w, lo, hi);
                acc1.z = fmaf(EB.y, lo, acc1.z); acc1.w = fmaf(EB.y, hi, acc1.w);
            }

            // reduce partials across the 8 groups (lane bits 3,4,5)
#pragma unroll
            for (int mk = 8; mk <= 32; mk <<= 1) {
                acc0.x += __shfl_xor(acc0.x, mk);
                acc0.y += __shfl_xor(acc0.y, mk);
                acc0.z += __shfl_xor(acc0.z, mk);
                acc0.w += __shfl_xor(acc0.w, mk);
                acc1.x += __shfl_xor(acc1.x, mk);
                acc1.y += __shfl_xor(acc1.y, mk);
                acc1.z += __shfl_xor(acc1.z, mk);
                acc1.w += __shfl_xor(acc1.w, mk);
            }

            if (prev) {
                const uint4 p = *reinterpret_cast<const uint4*>(&prev[(size_t)n * DD + c8]);
                float lo, hi;
                unpk_bf16(p.x, lo, hi);
                acc0.x = 2.f * acc0.x - lo; acc0.y = 2.f * acc0.y - hi;
                unpk_bf16(p.y, lo, hi);
                acc0.z = 2.f * acc0.z - lo; acc0.w = 2.f * acc0.w - hi;
                unpk_bf16(p.z, lo, hi);
                acc1.x = 2.f * acc1.x - lo; acc1.y = 2.f * acc1.y - hi;
                unpk_bf16(p.w, lo, hi);
                acc1.z = 2.f * acc1.z - lo; acc1.w = 2.f * acc1.w - hi;
            }
            if (g == 0) {
                *reinterpret_cast<uint4*>(&Tnext[(size_t)n * DD + c8]) =
                    make_uint4(pk_bf16(acc0.x, acc0.y), pk_bf16(acc0.z, acc0.w),
                               pk_bf16(acc1.x, acc1.y), pk_bf16(acc1.z, acc1.w));
            }
        }

        // Ts[nl][8j+g] = component g of this lane's 8 channels (static select)
        float val;
        switch (g) {
            case 0: val = acc0.x; break;
            case 1: val = acc0.y; break;
            case 2: val = acc0.z; break;
            case 3: val = acc0.w; break;
            case 4: val = acc1.x; break;
            case 5: val = acc1.y; break;
            case 6: val = acc1.z; break;
            default: val = acc1.w; break;
        }
        Ts[nl][c8 + g] = val;
    }
    __syncthreads();

    // ---- phase 2: out[nb0..nb0+63][:] += Ts @ Wk ----
    int r = threadIdx.x >> 4, c = threadIdx.x & 15;
    int r4 = r * 4, c4 = c * 4;
    float acc[4][4] = {};
#pragma unroll 4
    for (int d = 0; d < DD; ++d) {
        float a0 = Ts[r4 + 0][d], a1 = Ts[r4 + 1][d];
        float a2 = Ts[r4 + 2][d], a3 = Ts[r4 + 3][d];
        float4 b = *reinterpret_cast<const float4*>(&Ws[d * DD + c4]);
        acc[0][0] = fmaf(a0, b.x, acc[0][0]); acc[0][1] = fmaf(a0, b.y, acc[0][1]);
        acc[0][2] = fmaf(a0, b.z, acc[0][2]); acc[0][3] = fmaf(a0, b.w, acc[0][3]);
        acc[1][0] = fmaf(a1, b.x, acc[1][0]); acc[1][1] = fmaf(a1, b.y, acc[1][1]);
        acc[1][2] = fmaf(a1, b.z, acc[1][2]); acc[1][3] = fmaf(a1, b.w, acc[1][3]);
        acc[2][0] = fmaf(a2, b.x, acc[2][0]); acc[2][1] = fmaf(a2, b.y, acc[2][1]);
        acc[2][2] = fmaf(a2, b.z, acc[2][2]); acc[2][3] = fmaf(a2, b.w, acc[2][3]);
        acc[3][0] = fmaf(a3, b.x, acc[3][0]); acc[3][1] = fmaf(a3, b.y, acc[3][1]);
        acc[3][2] = fmaf(a3, b.z, acc[3][2]); acc[3][3] = fmaf(a3, b.w, acc[3][3]);
    }
#pragma unroll
    for (int i = 0; i < 4; ++i) {
        int n = nb0 + r4 + i;
        if (n < N) {
            float4 o = *reinterpret_cast<const float4*>(&out[(size_t)n * DD + c4]);
            o.x += acc[i][0]; o.y += acc[i][1];
            o.z += acc[i][2]; o.w += acc[i][3];
            *reinterpret_cast<float4*>(&out[(size_t)n * DD + c4]) = o;
        }
    }
}

// ---------------- launch ----------------

static inline size_t rup(size_t x) { return (x + 255) & ~(size_t)255; }

extern "C" void kernel_launch(void* const* d_in, const int* in_sizes, int n_in,
                              void* d_out, int out_size, void* d_ws, size_t ws_size,
                              hipStream_t stream) {
    const float* x    = (const float*)d_in[0];
    const int*   ei   = (const int*)  d_in[1];
    const float* ew   = (const float*)d_in[2];
    const float* W    = (const float*)d_in[3];
    const float* bias = (const float*)d_in[4];
    float* out = (float*)d_out;

    int N = in_sizes[0] / DD;
    int E = in_sizes[2];
    int K = in_sizes[3] / (DD * DD);

    size_t nb_bf = (size_t)N * DD * sizeof(unsigned short);  // bf16 T buffer
    int nb_scan = (N + 1 + 255) / 256;

    char* w = (char*)d_ws;
    unsigned short* xq   = (unsigned short*)w;  w += rup(nb_bf);
    unsigned short* bufA = (unsigned short*)w;  w += rup(nb_bf);
    unsigned short* bufB = (unsigned short*)w;  w += rup(nb_bf);
    float2* edges   = (float2*)w;               w += rup((size_t)E * sizeof(float2));
    int*    cnt     = (int*)w;                  w += rup((size_t)N * sizeof(int));
    int*    row_ptr = (int*)w;                  w += rup((size_t)(N + 1) * sizeof(int));
    int*    bsum    = (int*)w;                  w += rup((size_t)nb_scan * sizeof(int));

    int eb   = (E + 255) / 256;
    int gb64 = (N + 63) / 64;
    int n8   = (N * DD) / 8;
    int qb   = (n8 + 255) / 256;

    // ---- CSR build ----
    hipMemsetAsync(cnt, 0, (size_t)N * sizeof(int), stream);
    hist_kernel<<<eb, 256, 0, stream>>>(ei, cnt, E);
    scanA_kernel<<<nb_scan, 256, 0, stream>>>(cnt, bsum, N);
    scanB_kernel<<<1, 256, 0, stream>>>(bsum, nb_scan);
    scanC_kernel<<<nb_scan, 256, 0, stream>>>(cnt, bsum, row_ptr, N, E);
    hipMemcpyAsync(cnt, row_ptr, (size_t)N * sizeof(int),
                   hipMemcpyDeviceToDevice, stream);           // cnt -> cursor
    fill_kernel<<<eb, 256, 0, stream>>>(ei, ew, cnt, edges, E);

    // ---- quantize x for gathering ----
    quant_kernel<<<qb, 256, 0, stream>>>((const float4*)x, (uint4*)xq, n8);

    // ---- T_0 term (fp32 x) ----
    gemm_init_kernel<<<gb64, 256, 0, stream>>>(x, W, bias, out, N);

    if (K > 1) {
        // T_1 = prop(x); out += T_1 @ W_1
        prop_fused_kernel<<<gb64, 256, 0, stream>>>(
            xq, nullptr, edges, row_ptr, W + DD * DD, out, bufA, N);
    }

    // T_k = 2*prop(T_{k-1}) - T_{k-2}; out += T_k @ W_k
    // Rotation (bf16 buffers):
    //   k=2: prop(bufA, xq   -> bufB)
    //   k=3: prop(bufB, bufA -> bufA)   (Tnext aliases prev: safe)
    //   k=4: prop(bufA, bufB -> bufB)   ... alternating
    const unsigned short* prev = xq;
    unsigned short*       cur  = bufA;
    unsigned short*       nxt  = bufB;
    for (int k = 2; k < K; ++k) {
        prop_fused_kernel<<<gb64, 256, 0, stream>>>(
            cur, prev, edges, row_ptr, W + (size_t)k * DD * DD, out, nxt, N);
        unsigned short* old_cur = cur;
        cur  = nxt;
        prev = old_cur;
        nxt  = old_cur;
    }
}

// Round 9
// 443.567 us; speedup vs baseline: 1.6670x; 1.1106x over previous
//
#include <hip/hip_runtime.h>

#define DD 64

// ---------------- bf16 helpers (RTN-even) ----------------

__device__ __forceinline__ unsigned pk_bf16(float a, float b) {
    unsigned ua = __float_as_uint(a), ub = __float_as_uint(b);
    ua = (ua + 0x7fffu + ((ua >> 16) & 1u)) >> 16;          // low half
    ub = (ub + 0x7fffu + ((ub >> 16) & 1u)) & 0xffff0000u;  // high half
    return (ua & 0xffffu) | ub;
}
__device__ __forceinline__ void unpk_bf16(unsigned u, float& lo, float& hi) {
    lo = __uint_as_float(u << 16);
    hi = __uint_as_float(u & 0xffff0000u);
}

// ---------------- CSR build (by destination) ----------------

__global__ __launch_bounds__(256) void hist_kernel(
    const int* __restrict__ ei, int* __restrict__ cnt, int E)
{
    int e = blockIdx.x * 256 + threadIdx.x;
    if (e < E) atomicAdd(&cnt[ei[E + e]], 1);
}

__global__ __launch_bounds__(256) void scanA_kernel(
    const int* __restrict__ cnt, int* __restrict__ bsum, int N)
{
    __shared__ int s[256];
    int idx = blockIdx.x * 256 + threadIdx.x;
    s[threadIdx.x] = (idx < N) ? cnt[idx] : 0;
    __syncthreads();
    for (int off = 128; off > 0; off >>= 1) {
        if (threadIdx.x < off) s[threadIdx.x] += s[threadIdx.x + off];
        __syncthreads();
    }
    if (threadIdx.x == 0) bsum[blockIdx.x] = s[0];
}

__global__ __launch_bounds__(256) void scanB_kernel(int* __restrict__ bsum, int nb)
{
    __shared__ int s[256];
    int carry = 0;
    for (int base = 0; base < nb; base += 256) {
        int i = base + threadIdx.x;
        int v = (i < nb) ? bsum[i] : 0;
        s[threadIdx.x] = v;
        __syncthreads();
        for (int off = 1; off < 256; off <<= 1) {
            int t = (threadIdx.x >= off) ? s[threadIdx.x - off] : 0;
            __syncthreads();
            s[threadIdx.x] += t;
            __syncthreads();
        }
        if (i < nb) bsum[i] = carry + s[threadIdx.x] - v;   // exclusive
        int tot = s[255];
        __syncthreads();
        carry += tot;
    }
}

__global__ __launch_bounds__(256) void scanC_kernel(
    const int* __restrict__ cnt, const int* __restrict__ bsum,
    int* __restrict__ row_ptr, int N, int E)
{
    __shared__ int s[256];
    int idx = blockIdx.x * 256 + threadIdx.x;
    int v = (idx < N) ? cnt[idx] : 0;
    s[threadIdx.x] = v;
    __syncthreads();
    for (int off = 1; off < 256; off <<= 1) {
        int t = (threadIdx.x >= off) ? s[threadIdx.x - off] : 0;
        __syncthreads();
        s[threadIdx.x] += t;
        __syncthreads();
    }
    if (idx < N) row_ptr[idx] = s[threadIdx.x] - v + bsum[blockIdx.x];
    if (idx == N) row_ptr[N] = E;
}

__global__ __launch_bounds__(256) void fill_kernel(
    const int* __restrict__ ei, const float* __restrict__ ew,
    int* __restrict__ cursor, float2* __restrict__ edges, int E)
{
    int e = blockIdx.x * 256 + threadIdx.x;
    if (e >= E) return;
    int dst = ei[E + e];
    int pos = atomicAdd(&cursor[dst], 1);
    edges[pos] = make_float2(__int_as_float(ei[e]), ew[e]);
}

// quantize fp32 -> packed bf16 (8 elems / thread)
__global__ __launch_bounds__(256) void quant_kernel(
    const float4* __restrict__ src, uint4* __restrict__ dst, int n8)
{
    int i = blockIdx.x * 256 + threadIdx.x;
    if (i >= n8) return;
    float4 a = src[2 * i], b = src[2 * i + 1];
    dst[i] = make_uint4(pk_bf16(a.x, a.y), pk_bf16(a.z, a.w),
                        pk_bf16(b.x, b.y), pk_bf16(b.z, b.w));
}

// ---------------- compute kernels ----------------
// Block = 512 threads = 8 waves, owns 64 nodes (grid 782 -> ~3 blocks/CU,
// ~24 waves/CU resident). Phase 2: register-blocked 64x64x64 GEMM from LDS,
// thread (r,c)=(tx>>4, tx&15) owns 2x4 tile; Ts row-group stride 136 ≡ 8
// mod 32 -> 4 r-groups hit distinct banks (fixes round-8 2-way conflict).

// out[n][c] = bias[c] + sum_d x[n][d]*W0[d][c]   (T_0 term)
__global__ __launch_bounds__(512) void gemm_init_kernel(
    const float* __restrict__ x, const float* __restrict__ W,
    const float* __restrict__ bias, float* __restrict__ out, int N)
{
    __shared__ float Ws[DD * DD];
    __shared__ float Ts[64][68];
    for (int i = threadIdx.x; i < DD * DD; i += 512) Ws[i] = W[i];

    int nb0 = blockIdx.x * 64;
    int nl = threadIdx.x >> 3;       // 0..63
    int q  = threadIdx.x & 7;        // 0..7
    {
        int col = q * 8;
        float4 v0 = make_float4(0.f, 0.f, 0.f, 0.f), v1 = v0;
        if (nb0 + nl < N) {
            v0 = *reinterpret_cast<const float4*>(&x[(size_t)(nb0 + nl) * DD + col]);
            v1 = *reinterpret_cast<const float4*>(&x[(size_t)(nb0 + nl) * DD + col + 4]);
        }
        *reinterpret_cast<float4*>(&Ts[nl][col]) = v0;
        *reinterpret_cast<float4*>(&Ts[nl][col + 4]) = v1;
    }
    __syncthreads();

    int r = threadIdx.x >> 4, c = threadIdx.x & 15;
    int r2 = r * 2, c4 = c * 4;
    const float4 bb = *reinterpret_cast<const float4*>(&bias[c4]);
    float acc[2][4];
#pragma unroll
    for (int i = 0; i < 2; ++i) {
        acc[i][0] = bb.x; acc[i][1] = bb.y; acc[i][2] = bb.z; acc[i][3] = bb.w;
    }
#pragma unroll 8
    for (int d = 0; d < DD; ++d) {
        float a0 = Ts[r2 + 0][d], a1 = Ts[r2 + 1][d];
        float4 b = *reinterpret_cast<const float4*>(&Ws[d * DD + c4]);
        acc[0][0] = fmaf(a0, b.x, acc[0][0]); acc[0][1] = fmaf(a0, b.y, acc[0][1]);
        acc[0][2] = fmaf(a0, b.z, acc[0][2]); acc[0][3] = fmaf(a0, b.w, acc[0][3]);
        acc[1][0] = fmaf(a1, b.x, acc[1][0]); acc[1][1] = fmaf(a1, b.y, acc[1][1]);
        acc[1][2] = fmaf(a1, b.z, acc[1][2]); acc[1][3] = fmaf(a1, b.w, acc[1][3]);
    }
#pragma unroll
    for (int i = 0; i < 2; ++i) {
        int n = nb0 + r2 + i;
        if (n < N) {
            float4 o = make_float4(acc[i][0], acc[i][1], acc[i][2], acc[i][3]);
            *reinterpret_cast<float4*>(&out[(size_t)n * DD + c4]) = o;
        }
    }
}

// Fused propagate + recurrence + GEMM accumulate, bf16 T-storage.
// Phase 1: wave wv owns nodes wv*8..wv*8+7, gathered TWO at a time
// (4 m-iterations): 8 groups x 8 lanes per node, 4 edge-meta loads + 8 row
// gathers in flight per iteration. Xor reduce (8/16/32), recurrence vs prev
// (bf16), Tnext (bf16) by g==0 lanes, Ts (fp32) one ds_write_b32/node/lane.
// Phase 2: register-blocked GEMM, out += Ts @ Wk.
// ALIASING CONTRACT: Tnext may alias prev; must NOT alias h.
__global__ __launch_bounds__(512) void prop_fused_kernel(
    const unsigned short* __restrict__ h, const unsigned short* __restrict__ prev,
    const float2* __restrict__ edges, const int* __restrict__ row_ptr,
    const float* __restrict__ Wk, float* __restrict__ out,
    unsigned short* __restrict__ Tnext, int N)
{
    __shared__ float Ws[DD * DD];
    __shared__ float Ts[64][68];
    for (int i = threadIdx.x; i < DD * DD; i += 512) Ws[i] = Wk[i];

    int lane = threadIdx.x & 63;
    int wv   = threadIdx.x >> 6;   // 0..7
    int g  = lane >> 3;            // edge group 0..7
    int j  = lane & 7;
    int c8 = j << 3;               // channel base: 8 bf16 channels per lane
    int nb0 = blockIdx.x * 64;
    const float2 zed = make_float2(__int_as_float(0), 0.f);

    for (int m = 0; m < 4; ++m) {
        int nl0 = wv * 8 + 2 * m, nl1 = nl0 + 1;
        int n0 = nb0 + nl0, n1 = nb0 + nl1;
        bool v0 = n0 < N, v1 = n1 < N;

        // consecutive rows: end0 == beg1
        int beg0 = 0, end0 = 0, beg1 = 0, end1 = 0;
        if (v0) { beg0 = row_ptr[n0]; end0 = row_ptr[n0 + 1]; }
        if (v1) { beg1 = end0; end1 = row_ptr[n1 + 1]; }

        float4 A0 = make_float4(0.f, 0.f, 0.f, 0.f), A1 = A0;  // node0, ch c8..c8+7
        float4 B0 = A0, B1 = A0;                               // node1

        int b0 = beg0, b1 = beg1;
        while (b0 < end0 || b1 < end1) {
            float2 EA0 = (b0 + g     < end0) ? edges[b0 + g]     : zed;
            float2 EB0 = (b0 + 8 + g < end0) ? edges[b0 + 8 + g] : zed;
            float2 EA1 = (b1 + g     < end1) ? edges[b1 + g]     : zed;
            float2 EB1 = (b1 + 8 + g < end1) ? edges[b1 + 8 + g] : zed;
            const uint4 wa0 = *reinterpret_cast<const uint4*>(
                &h[(size_t)__float_as_int(EA0.x) * DD + c8]);
            const uint4 wb0 = *reinterpret_cast<const uint4*>(
                &h[(size_t)__float_as_int(EB0.x) * DD + c8]);
            const uint4 wa1 = *reinterpret_cast<const uint4*>(
                &h[(size_t)__float_as_int(EA1.x) * DD + c8]);
            const uint4 wb1 = *reinterpret_cast<const uint4*>(
                &h[(size_t)__float_as_int(EB1.x) * DD + c8]);
            float lo, hi;
            unpk_bf16(wa0.x, lo, hi); A0.x = fmaf(EA0.y, lo, A0.x); A0.y = fmaf(EA0.y, hi, A0.y);
            unpk_bf16(wa0.y, lo, hi); A0.z = fmaf(EA0.y, lo, A0.z); A0.w = fmaf(EA0.y, hi, A0.w);
            unpk_bf16(wa0.z, lo, hi); A1.x = fmaf(EA0.y, lo, A1.x); A1.y = fmaf(EA0.y, hi, A1.y);
            unpk_bf16(wa0.w, lo, hi); A1.z = fmaf(EA0.y, lo, A1.z); A1.w = fmaf(EA0.y, hi, A1.w);
            unpk_bf16(wb0.x, lo, hi); A0.x = fmaf(EB0.y, lo, A0.x); A0.y = fmaf(EB0.y, hi, A0.y);
            unpk_bf16(wb0.y, lo, hi); A0.z = fmaf(EB0.y, lo, A0.z); A0.w = fmaf(EB0.y, hi, A0.w);
            unpk_bf16(wb0.z, lo, hi); A1.x = fmaf(EB0.y, lo, A1.x); A1.y = fmaf(EB0.y, hi, A1.y);
            unpk_bf16(wb0.w, lo, hi); A1.z = fmaf(EB0.y, lo, A1.z); A1.w = fmaf(EB0.y, hi, A1.w);
            unpk_bf16(wa1.x, lo, hi); B0.x = fmaf(EA1.y, lo, B0.x); B0.y = fmaf(EA1.y, hi, B0.y);
            unpk_bf16(wa1.y, lo, hi); B0.z = fmaf(EA1.y, lo, B0.z); B0.w = fmaf(EA1.y, hi, B0.w);
            unpk_bf16(wa1.z, lo, hi); B1.x = fmaf(EA1.y, lo, B1.x); B1.y = fmaf(EA1.y, hi, B1.y);
            unpk_bf16(wa1.w, lo, hi); B1.z = fmaf(EA1.y, lo, B1.z); B1.w = fmaf(EA1.y, hi, B1.w);
            unpk_bf16(wb1.x, lo, hi); B0.x = fmaf(EB1.y, lo, B0.x); B0.y = fmaf(EB1.y, hi, B0.y);
            unpk_bf16(wb1.y, lo, hi); B0.z = fmaf(EB1.y, lo, B0.z); B0.w = fmaf(EB1.y, hi, B0.w);
            unpk_bf16(wb1.z, lo, hi); B1.x = fmaf(EB1.y, lo, B1.x); B1.y = fmaf(EB1.y, hi, B1.y);
            unpk_bf16(wb1.w, lo, hi); B1.z = fmaf(EB1.y, lo, B1.z); B1.w = fmaf(EB1.y, hi, B1.w);
            b0 += 16; b1 += 16;
        }

        // reduce partials across the 8 groups (lane bits 3,4,5), both nodes
#pragma unroll
        for (int mk = 8; mk <= 32; mk <<= 1) {
            A0.x += __shfl_xor(A0.x, mk); A0.y += __shfl_xor(A0.y, mk);
            A0.z += __shfl_xor(A0.z, mk); A0.w += __shfl_xor(A0.w, mk);
            A1.x += __shfl_xor(A1.x, mk); A1.y += __shfl_xor(A1.y, mk);
            A1.z += __shfl_xor(A1.z, mk); A1.w += __shfl_xor(A1.w, mk);
            B0.x += __shfl_xor(B0.x, mk); B0.y += __shfl_xor(B0.y, mk);
            B0.z += __shfl_xor(B0.z, mk); B0.w += __shfl_xor(B0.w, mk);
            B1.x += __shfl_xor(B1.x, mk); B1.y += __shfl_xor(B1.y, mk);
            B1.z += __shfl_xor(B1.z, mk); B1.w += __shfl_xor(B1.w, mk);
        }

        if (prev) {
            if (v0) {
                const uint4 p = *reinterpret_cast<const uint4*>(&prev[(size_t)n0 * DD + c8]);
                float lo, hi;
                unpk_bf16(p.x, lo, hi); A0.x = 2.f * A0.x - lo; A0.y = 2.f * A0.y - hi;
                unpk_bf16(p.y, lo, hi); A0.z = 2.f * A0.z - lo; A0.w = 2.f * A0.w - hi;
                unpk_bf16(p.z, lo, hi); A1.x = 2.f * A1.x - lo; A1.y = 2.f * A1.y - hi;
                unpk_bf16(p.w, lo, hi); A1.z = 2.f * A1.z - lo; A1.w = 2.f * A1.w - hi;
            }
            if (v1) {
                const uint4 p = *reinterpret_cast<const uint4*>(&prev[(size_t)n1 * DD + c8]);
                float lo, hi;
                unpk_bf16(p.x, lo, hi); B0.x = 2.f * B0.x - lo; B0.y = 2.f * B0.y - hi;
                unpk_bf16(p.y, lo, hi); B0.z = 2.f * B0.z - lo; B0.w = 2.f * B0.w - hi;
                unpk_bf16(p.z, lo, hi); B1.x = 2.f * B1.x - lo; B1.y = 2.f * B1.y - hi;
                unpk_bf16(p.w, lo, hi); B1.z = 2.f * B1.z - lo; B1.w = 2.f * B1.w - hi;
            }
        }
        if (g == 0) {
            if (v0)
                *reinterpret_cast<uint4*>(&Tnext[(size_t)n0 * DD + c8]) =
                    make_uint4(pk_bf16(A0.x, A0.y), pk_bf16(A0.z, A0.w),
                               pk_bf16(A1.x, A1.y), pk_bf16(A1.z, A1.w));
            if (v1)
                *reinterpret_cast<uint4*>(&Tnext[(size_t)n1 * DD + c8]) =
                    make_uint4(pk_bf16(B0.x, B0.y), pk_bf16(B0.z, B0.w),
                               pk_bf16(B1.x, B1.y), pk_bf16(B1.z, B1.w));
        }

        // Ts[nl][8j+g] = component g (static select); banks 2-way -> free
        float va, vb;
        switch (g) {
            case 0: va = A0.x; vb = B0.x; break;
            case 1: va = A0.y; vb = B0.y; break;
            case 2: va = A0.z; vb = B0.z; break;
            case 3: va = A0.w; vb = B0.w; break;
            case 4: va = A1.x; vb = B1.x; break;
            case 5: va = A1.y; vb = B1.y; break;
            case 6: va = A1.z; vb = B1.z; break;
            default: va = A1.w; vb = B1.w; break;
        }
        Ts[nl0][c8 + g] = va;
        Ts[nl1][c8 + g] = vb;
    }
    __syncthreads();

    // ---- phase 2: out[nb0..nb0+63][:] += Ts @ Wk ----
    int r = threadIdx.x >> 4, c = threadIdx.x & 15;
    int r2 = r * 2, c4 = c * 4;
    float acc[2][4] = {};
#pragma unroll 8
    for (int d = 0; d < DD; ++d) {
        float a0 = Ts[r2 + 0][d], a1 = Ts[r2 + 1][d];
        float4 b = *reinterpret_cast<const float4*>(&Ws[d * DD + c4]);
        acc[0][0] = fmaf(a0, b.x, acc[0][0]); acc[0][1] = fmaf(a0, b.y, acc[0][1]);
        acc[0][2] = fmaf(a0, b.z, acc[0][2]); acc[0][3] = fmaf(a0, b.w, acc[0][3]);
        acc[1][0] = fmaf(a1, b.x, acc[1][0]); acc[1][1] = fmaf(a1, b.y, acc[1][1]);
        acc[1][2] = fmaf(a1, b.z, acc[1][2]); acc[1][3] = fmaf(a1, b.w, acc[1][3]);
    }
#pragma unroll
    for (int i = 0; i < 2; ++i) {
        int n = nb0 + r2 + i;
        if (n < N) {
            float4 o = *reinterpret_cast<const float4*>(&out[(size_t)n * DD + c4]);
            o.x += acc[i][0]; o.y += acc[i][1];
            o.z += acc[i][2]; o.w += acc[i][3];
            *reinterpret_cast<float4*>(&out[(size_t)n * DD + c4]) = o;
        }
    }
}

// ---------------- launch ----------------

static inline size_t rup(size_t x) { return (x + 255) & ~(size_t)255; }

extern "C" void kernel_launch(void* const* d_in, const int* in_sizes, int n_in,
                              void* d_out, int out_size, void* d_ws, size_t ws_size,
                              hipStream_t stream) {
    const float* x    = (const float*)d_in[0];
    const int*   ei   = (const int*)  d_in[1];
    const float* ew   = (const float*)d_in[2];
    const float* W    = (const float*)d_in[3];
    const float* bias = (const float*)d_in[4];
    float* out = (float*)d_out;

    int N = in_sizes[0] / DD;
    int E = in_sizes[2];
    int K = in_sizes[3] / (DD * DD);

    size_t nb_bf = (size_t)N * DD * sizeof(unsigned short);  // bf16 T buffer
    int nb_scan = (N + 1 + 255) / 256;

    char* w = (char*)d_ws;
    unsigned short* xq   = (unsigned short*)w;  w += rup(nb_bf);
    unsigned short* bufA = (unsigned short*)w;  w += rup(nb_bf);
    unsigned short* bufB = (unsigned short*)w;  w += rup(nb_bf);
    float2* edges   = (float2*)w;               w += rup((size_t)E * sizeof(float2));
    int*    cnt     = (int*)w;                  w += rup((size_t)N * sizeof(int));
    int*    row_ptr = (int*)w;                  w += rup((size_t)(N + 1) * sizeof(int));
    int*    bsum    = (int*)w;                  w += rup((size_t)nb_scan * sizeof(int));

    int eb   = (E + 255) / 256;
    int gb64 = (N + 63) / 64;
    int n8   = (N * DD) / 8;
    int qb   = (n8 + 255) / 256;

    // ---- CSR build ----
    hipMemsetAsync(cnt, 0, (size_t)N * sizeof(int), stream);
    hist_kernel<<<eb, 256, 0, stream>>>(ei, cnt, E);
    scanA_kernel<<<nb_scan, 256, 0, stream>>>(cnt, bsum, N);
    scanB_kernel<<<1, 256, 0, stream>>>(bsum, nb_scan);
    scanC_kernel<<<nb_scan, 256, 0, stream>>>(cnt, bsum, row_ptr, N, E);
    hipMemcpyAsync(cnt, row_ptr, (size_t)N * sizeof(int),
                   hipMemcpyDeviceToDevice, stream);           // cnt -> cursor
    fill_kernel<<<eb, 256, 0, stream>>>(ei, ew, cnt, edges, E);

    // ---- quantize x for gathering ----
    quant_kernel<<<qb, 256, 0, stream>>>((const float4*)x, (uint4*)xq, n8);

    // ---- T_0 term (fp32 x) ----
    gemm_init_kernel<<<gb64, 512, 0, stream>>>(x, W, bias, out, N);

    if (K > 1) {
        // T_1 = prop(x); out += T_1 @ W_1
        prop_fused_kernel<<<gb64, 512, 0, stream>>>(
            xq, nullptr, edges, row_ptr, W + DD * DD, out, bufA, N);
    }

    // T_k = 2*prop(T_{k-1}) - T_{k-2}; out += T_k @ W_k
    // Rotation (bf16 buffers):
    //   k=2: prop(bufA, xq   -> bufB)
    //   k=3: prop(bufB, bufA -> bufA)   (Tnext aliases prev: safe)
    //   k=4: prop(bufA, bufB -> bufB)   ... alternating
    const unsigned short* prev = xq;
    unsigned short*       cur  = bufA;
    unsigned short*       nxt  = bufB;
    for (int k = 2; k < K; ++k) {
        prop_fused_kernel<<<gb64, 512, 0, stream>>>(
            cur, prev, edges, row_ptr, W + (size_t)k * DD * DD, out, nxt, N);
        unsigned short* old_cur = cur;
        cur  = nxt;
        prev = old_cur;
        nxt  = old_cur;
    }
}

// Round 10
// 345.671 us; speedup vs baseline: 2.1391x; 1.2832x over previous
//
#include <hip/hip_runtime.h>

#define DD 64

// ---------------- bf16 helpers (RTN-even) ----------------

__device__ __forceinline__ unsigned pk_bf16(float a, float b) {
    unsigned ua = __float_as_uint(a), ub = __float_as_uint(b);
    ua = (ua + 0x7fffu + ((ua >> 16) & 1u)) >> 16;
    ub = (ub + 0x7fffu + ((ub >> 16) & 1u)) & 0xffff0000u;
    return (ua & 0xffffu) | ub;
}
__device__ __forceinline__ void unpk_bf16(unsigned u, float& lo, float& hi) {
    lo = __uint_as_float(u << 16);
    hi = __uint_as_float(u & 0xffff0000u);
}

// ---------------- CSR build (by destination) ----------------

__global__ __launch_bounds__(256) void hist_kernel(
    const int* __restrict__ ei, int* __restrict__ cnt, int E)
{
    int e = blockIdx.x * 256 + threadIdx.x;
    if (e < E) atomicAdd(&cnt[ei[E + e]], 1);
}

__global__ __launch_bounds__(256) void scanA_kernel(
    const int* __restrict__ cnt, int* __restrict__ bsum, int N)
{
    __shared__ int s[256];
    int idx = blockIdx.x * 256 + threadIdx.x;
    s[threadIdx.x] = (idx < N) ? cnt[idx] : 0;
    __syncthreads();
    for (int off = 128; off > 0; off >>= 1) {
        if (threadIdx.x < off) s[threadIdx.x] += s[threadIdx.x + off];
        __syncthreads();
    }
    if (threadIdx.x == 0) bsum[blockIdx.x] = s[0];
}

__global__ __launch_bounds__(256) void scanB_kernel(int* __restrict__ bsum, int nb)
{
    __shared__ int s[256];
    int carry = 0;
    for (int base = 0; base < nb; base += 256) {
        int i = base + threadIdx.x;
        int v = (i < nb) ? bsum[i] : 0;
        s[threadIdx.x] = v;
        __syncthreads();
        for (int off = 1; off < 256; off <<= 1) {
            int t = (threadIdx.x >= off) ? s[threadIdx.x - off] : 0;
            __syncthreads();
            s[threadIdx.x] += t;
            __syncthreads();
        }
        if (i < nb) bsum[i] = carry + s[threadIdx.x] - v;   // exclusive
        int tot = s[255];
        __syncthreads();
        carry += tot;
    }
}

__global__ __launch_bounds__(256) void scanC_kernel(
    const int* __restrict__ cnt, const int* __restrict__ bsum,
    int* __restrict__ row_ptr, int N, int E)
{
    __shared__ int s[256];
    int idx = blockIdx.x * 256 + threadIdx.x;
    int v = (idx < N) ? cnt[idx] : 0;
    s[threadIdx.x] = v;
    __syncthreads();
    for (int off = 1; off < 256; off <<= 1) {
        int t = (threadIdx.x >= off) ? s[threadIdx.x - off] : 0;
        __syncthreads();
        s[threadIdx.x] += t;
        __syncthreads();
    }
    if (idx < N) row_ptr[idx] = s[threadIdx.x] - v + bsum[blockIdx.x];
    if (idx == N) row_ptr[N] = E;
}

__global__ __launch_bounds__(256) void fill_kernel(
    const int* __restrict__ ei, const float* __restrict__ ew,
    int* __restrict__ cursor, float2* __restrict__ edges, int E)
{
    int e = blockIdx.x * 256 + threadIdx.x;
    if (e >= E) return;
    int dst = ei[E + e];
    int pos = atomicAdd(&cursor[dst], 1);
    edges[pos] = make_float2(__int_as_float(ei[e]), ew[e]);
}

// quantize fp32 -> packed bf16 (8 elems / thread)
__global__ __launch_bounds__(256) void quant_kernel(
    const float4* __restrict__ src, uint4* __restrict__ dst, int n8)
{
    int i = blockIdx.x * 256 + threadIdx.x;
    if (i >= n8) return;
    float4 a = src[2 * i], b = src[2 * i + 1];
    dst[i] = make_uint4(pk_bf16(a.x, a.y), pk_bf16(a.z, a.w),
                        pk_bf16(b.x, b.y), pk_bf16(b.z, b.w));
}

// ---------------- pure gather propagate (no LDS, no barrier) ----------------
// One 64-lane wave per 2 nodes, 4 waves/block, grid = N/8 blocks.
// 8 groups x 8 lanes per node; per while-iter: 4 edge-meta loads + 4 uint4
// row gathers in flight. Xor reduce (8/16/32), recurrence vs prev (bf16),
// Tnext (bf16) written by g==0 lanes. No out traffic (deferred GEMM).
// ALIASING CONTRACT: Tnext must not alias h or prev.
__global__ __launch_bounds__(256) void prop_kernel(
    const unsigned short* __restrict__ h, const unsigned short* __restrict__ prev,
    const float2* __restrict__ edges, const int* __restrict__ row_ptr,
    unsigned short* __restrict__ Tnext, int N)
{
    int lane = threadIdx.x & 63;
    int wid  = (blockIdx.x * 256 + threadIdx.x) >> 6;  // global wave id
    int n0 = wid * 2, n1 = n0 + 1;
    if (n0 >= N) return;
    bool v1 = n1 < N;

    int g  = lane >> 3;
    int c8 = (lane & 7) << 3;
    const float2 zed = make_float2(__int_as_float(0), 0.f);

    int beg0 = row_ptr[n0];
    int end0 = row_ptr[n0 + 1];
    int beg1 = end0;
    int end1 = v1 ? row_ptr[n1 + 1] : end0;

    float4 A0 = make_float4(0.f, 0.f, 0.f, 0.f), A1 = A0;  // node0
    float4 B0 = A0, B1 = A0;                               // node1

    int b0 = beg0, b1 = beg1;
    while (b0 < end0 || b1 < end1) {
        float2 EA0 = (b0 + g     < end0) ? edges[b0 + g]     : zed;
        float2 EB0 = (b0 + 8 + g < end0) ? edges[b0 + 8 + g] : zed;
        float2 EA1 = (b1 + g     < end1) ? edges[b1 + g]     : zed;
        float2 EB1 = (b1 + 8 + g < end1) ? edges[b1 + 8 + g] : zed;
        const uint4 wa0 = *reinterpret_cast<const uint4*>(
            &h[(size_t)__float_as_int(EA0.x) * DD + c8]);
        const uint4 wb0 = *reinterpret_cast<const uint4*>(
            &h[(size_t)__float_as_int(EB0.x) * DD + c8]);
        const uint4 wa1 = *reinterpret_cast<const uint4*>(
            &h[(size_t)__float_as_int(EA1.x) * DD + c8]);
        const uint4 wb1 = *reinterpret_cast<const uint4*>(
            &h[(size_t)__float_as_int(EB1.x) * DD + c8]);
        float lo, hi;
        unpk_bf16(wa0.x, lo, hi); A0.x = fmaf(EA0.y, lo, A0.x); A0.y = fmaf(EA0.y, hi, A0.y);
        unpk_bf16(wa0.y, lo, hi); A0.z = fmaf(EA0.y, lo, A0.z); A0.w = fmaf(EA0.y, hi, A0.w);
        unpk_bf16(wa0.z, lo, hi); A1.x = fmaf(EA0.y, lo, A1.x); A1.y = fmaf(EA0.y, hi, A1.y);
        unpk_bf16(wa0.w, lo, hi); A1.z = fmaf(EA0.y, lo, A1.z); A1.w = fmaf(EA0.y, hi, A1.w);
        unpk_bf16(wb0.x, lo, hi); A0.x = fmaf(EB0.y, lo, A0.x); A0.y = fmaf(EB0.y, hi, A0.y);
        unpk_bf16(wb0.y, lo, hi); A0.z = fmaf(EB0.y, lo, A0.z); A0.w = fmaf(EB0.y, hi, A0.w);
        unpk_bf16(wb0.z, lo, hi); A1.x = fmaf(EB0.y, lo, A1.x); A1.y = fmaf(EB0.y, hi, A1.y);
        unpk_bf16(wb0.w, lo, hi); A1.z = fmaf(EB0.y, lo, A1.z); A1.w = fmaf(EB0.y, hi, A1.w);
        unpk_bf16(wa1.x, lo, hi); B0.x = fmaf(EA1.y, lo, B0.x); B0.y = fmaf(EA1.y, hi, B0.y);
        unpk_bf16(wa1.y, lo, hi); B0.z = fmaf(EA1.y, lo, B0.z); B0.w = fmaf(EA1.y, hi, B0.w);
        unpk_bf16(wa1.z, lo, hi); B1.x = fmaf(EA1.y, lo, B1.x); B1.y = fmaf(EA1.y, hi, B1.y);
        unpk_bf16(wa1.w, lo, hi); B1.z = fmaf(EA1.y, lo, B1.z); B1.w = fmaf(EA1.y, hi, B1.w);
        unpk_bf16(wb1.x, lo, hi); B0.x = fmaf(EB1.y, lo, B0.x); B0.y = fmaf(EB1.y, hi, B0.y);
        unpk_bf16(wb1.y, lo, hi); B0.z = fmaf(EB1.y, lo, B0.z); B0.w = fmaf(EB1.y, hi, B0.w);
        unpk_bf16(wb1.z, lo, hi); B1.x = fmaf(EB1.y, lo, B1.x); B1.y = fmaf(EB1.y, hi, B1.y);
        unpk_bf16(wb1.w, lo, hi); B1.z = fmaf(EB1.y, lo, B1.z); B1.w = fmaf(EB1.y, hi, B1.w);
        b0 += 16; b1 += 16;
    }

#pragma unroll
    for (int mk = 8; mk <= 32; mk <<= 1) {
        A0.x += __shfl_xor(A0.x, mk); A0.y += __shfl_xor(A0.y, mk);
        A0.z += __shfl_xor(A0.z, mk); A0.w += __shfl_xor(A0.w, mk);
        A1.x += __shfl_xor(A1.x, mk); A1.y += __shfl_xor(A1.y, mk);
        A1.z += __shfl_xor(A1.z, mk); A1.w += __shfl_xor(A1.w, mk);
        B0.x += __shfl_xor(B0.x, mk); B0.y += __shfl_xor(B0.y, mk);
        B0.z += __shfl_xor(B0.z, mk); B0.w += __shfl_xor(B0.w, mk);
        B1.x += __shfl_xor(B1.x, mk); B1.y += __shfl_xor(B1.y, mk);
        B1.z += __shfl_xor(B1.z, mk); B1.w += __shfl_xor(B1.w, mk);
    }

    if (prev) {
        {
            const uint4 p = *reinterpret_cast<const uint4*>(&prev[(size_t)n0 * DD + c8]);
            float lo, hi;
            unpk_bf16(p.x, lo, hi); A0.x = 2.f * A0.x - lo; A0.y = 2.f * A0.y - hi;
            unpk_bf16(p.y, lo, hi); A0.z = 2.f * A0.z - lo; A0.w = 2.f * A0.w - hi;
            unpk_bf16(p.z, lo, hi); A1.x = 2.f * A1.x - lo; A1.y = 2.f * A1.y - hi;
            unpk_bf16(p.w, lo, hi); A1.z = 2.f * A1.z - lo; A1.w = 2.f * A1.w - hi;
        }
        if (v1) {
            const uint4 p = *reinterpret_cast<const uint4*>(&prev[(size_t)n1 * DD + c8]);
            float lo, hi;
            unpk_bf16(p.x, lo, hi); B0.x = 2.f * B0.x - lo; B0.y = 2.f * B0.y - hi;
            unpk_bf16(p.y, lo, hi); B0.z = 2.f * B0.z - lo; B0.w = 2.f * B0.w - hi;
            unpk_bf16(p.z, lo, hi); B1.x = 2.f * B1.x - lo; B1.y = 2.f * B1.y - hi;
            unpk_bf16(p.w, lo, hi); B1.z = 2.f * B1.z - lo; B1.w = 2.f * B1.w - hi;
        }
    }
    if (g == 0) {
        *reinterpret_cast<uint4*>(&Tnext[(size_t)n0 * DD + c8]) =
            make_uint4(pk_bf16(A0.x, A0.y), pk_bf16(A0.z, A0.w),
                       pk_bf16(A1.x, A1.y), pk_bf16(A1.z, A1.w));
        if (v1)
            *reinterpret_cast<uint4*>(&Tnext[(size_t)n1 * DD + c8]) =
                make_uint4(pk_bf16(B0.x, B0.y), pk_bf16(B0.z, B0.w),
                           pk_bf16(B1.x, B1.y), pk_bf16(B1.z, B1.w));
    }
}

// ---------------- mega GEMM: out (+)= bias + sum_kc Ts{kc} @ W{kc} ----------
// Block = 512 threads, 64 nodes. Loop over up to 4 orders: stage T_k (bf16 ->
// fp32 LDS Ts[64][68]) + W_k (16KB), register-blocked 2x4 accumulate.
// init=1: acc starts at bias, out overwritten (no out read).
// init=0: acc starts 0, out += acc.
__global__ __launch_bounds__(512) void mega_gemm_kernel(
    const unsigned short* __restrict__ T0, const unsigned short* __restrict__ T1,
    const unsigned short* __restrict__ T2, const unsigned short* __restrict__ T3,
    const float* __restrict__ W, const float* __restrict__ bias,
    float* __restrict__ out, int N, int nord, int init)
{
    __shared__ float Ws[DD * DD];
    __shared__ float Ts[64][68];
    const unsigned short* Tl[4] = { T0, T1, T2, T3 };

    int nb0 = blockIdx.x * 64;
    int r = threadIdx.x >> 4, c = threadIdx.x & 15;   // r 0..31, c 0..15
    int r2 = r * 2, c4 = c * 4;

    float acc[2][4];
    if (init) {
        const float4 bb = *reinterpret_cast<const float4*>(&bias[c4]);
#pragma unroll
        for (int i = 0; i < 2; ++i) {
            acc[i][0] = bb.x; acc[i][1] = bb.y; acc[i][2] = bb.z; acc[i][3] = bb.w;
        }
    } else {
#pragma unroll
        for (int i = 0; i < 2; ++i)
            acc[i][0] = acc[i][1] = acc[i][2] = acc[i][3] = 0.f;
    }

    int nl = threadIdx.x >> 3, q = threadIdx.x & 7;
    for (int kc = 0; kc < nord; ++kc) {
        __syncthreads();   // previous iteration's reads done before overwrite
        for (int i = threadIdx.x; i < DD * DD; i += 512)
            Ws[i] = W[kc * DD * DD + i];
        {
            uint4 u = make_uint4(0, 0, 0, 0);
            if (nb0 + nl < N)
                u = *reinterpret_cast<const uint4*>(
                    &Tl[kc][(size_t)(nb0 + nl) * DD + q * 8]);
            float f0, f1, f2, f3, f4, f5, f6, f7;
            unpk_bf16(u.x, f0, f1); unpk_bf16(u.y, f2, f3);
            unpk_bf16(u.z, f4, f5); unpk_bf16(u.w, f6, f7);
            *reinterpret_cast<float4*>(&Ts[nl][q * 8])     = make_float4(f0, f1, f2, f3);
            *reinterpret_cast<float4*>(&Ts[nl][q * 8 + 4]) = make_float4(f4, f5, f6, f7);
        }
        __syncthreads();
#pragma unroll 8
        for (int d = 0; d < DD; ++d) {
            float a0 = Ts[r2 + 0][d], a1 = Ts[r2 + 1][d];
            float4 b = *reinterpret_cast<const float4*>(&Ws[d * DD + c4]);
            acc[0][0] = fmaf(a0, b.x, acc[0][0]); acc[0][1] = fmaf(a0, b.y, acc[0][1]);
            acc[0][2] = fmaf(a0, b.z, acc[0][2]); acc[0][3] = fmaf(a0, b.w, acc[0][3]);
            acc[1][0] = fmaf(a1, b.x, acc[1][0]); acc[1][1] = fmaf(a1, b.y, acc[1][1]);
            acc[1][2] = fmaf(a1, b.z, acc[1][2]); acc[1][3] = fmaf(a1, b.w, acc[1][3]);
        }
    }

#pragma unroll
    for (int i = 0; i < 2; ++i) {
        int n = nb0 + r2 + i;
        if (n < N) {
            float4 o = make_float4(acc[i][0], acc[i][1], acc[i][2], acc[i][3]);
            if (!init) {
                float4 p = *reinterpret_cast<const float4*>(&out[(size_t)n * DD + c4]);
                o.x += p.x; o.y += p.y; o.z += p.z; o.w += p.w;
            }
            *reinterpret_cast<float4*>(&out[(size_t)n * DD + c4]) = o;
        }
    }
}

// ---------------- launch ----------------

static inline size_t rup(size_t x) { return (x + 255) & ~(size_t)255; }

extern "C" void kernel_launch(void* const* d_in, const int* in_sizes, int n_in,
                              void* d_out, int out_size, void* d_ws, size_t ws_size,
                              hipStream_t stream) {
    const float* x    = (const float*)d_in[0];
    const int*   ei   = (const int*)  d_in[1];
    const float* ew   = (const float*)d_in[2];
    const float* W    = (const float*)d_in[3];
    const float* bias = (const float*)d_in[4];
    float* out = (float*)d_out;

    int N = in_sizes[0] / DD;
    int E = in_sizes[2];
    int K = in_sizes[3] / (DD * DD);   // = 8

    size_t nb_bf = (size_t)N * DD * sizeof(unsigned short);
    int nb_scan = (N + 1 + 255) / 256;

    // 5-buffer ring: T_k lives in B[k % 5]. With 4-order GEMM chunks the
    // buffer of T_{k-5} has been consumed by the chunk GEMM before T_k
    // overwrites it (launch order below guarantees this).
    char* w = (char*)d_ws;
    unsigned short* B[5];
    for (int i = 0; i < 5; ++i) { B[i] = (unsigned short*)w; w += rup(nb_bf); }
    float2* edges   = (float2*)w;  w += rup((size_t)E * sizeof(float2));
    int*    cnt     = (int*)w;     w += rup((size_t)N * sizeof(int));
    int*    row_ptr = (int*)w;     w += rup((size_t)(N + 1) * sizeof(int));
    int*    bsum    = (int*)w;     w += rup((size_t)nb_scan * sizeof(int));

    int eb   = (E + 255) / 256;
    int pb   = (N + 7) / 8;        // prop: 4 waves x 2 nodes per block
    int gb64 = (N + 63) / 64;
    int n8   = (N * DD) / 8;
    int qb   = (n8 + 255) / 256;

    // ---- CSR build ----
    hipMemsetAsync(cnt, 0, (size_t)N * sizeof(int), stream);
    hist_kernel<<<eb, 256, 0, stream>>>(ei, cnt, E);
    scanA_kernel<<<nb_scan, 256, 0, stream>>>(cnt, bsum, N);
    scanB_kernel<<<1, 256, 0, stream>>>(bsum, nb_scan);
    scanC_kernel<<<nb_scan, 256, 0, stream>>>(cnt, bsum, row_ptr, N, E);
    hipMemcpyAsync(cnt, row_ptr, (size_t)N * sizeof(int),
                   hipMemcpyDeviceToDevice, stream);           // cnt -> cursor
    fill_kernel<<<eb, 256, 0, stream>>>(ei, ew, cnt, edges, E);

    // ---- T_0 = bf16(x) ----
    quant_kernel<<<qb, 256, 0, stream>>>((const float4*)x, (uint4*)B[0], n8);

    // ---- recursion + chunked GEMM ----
    // T_1 = prop(T_0); T_k = 2*prop(T_{k-1}) - T_{k-2}
    // after T_{4c+3}: mega chunk c (orders 4c..4c+3)
    int done = 0;   // orders GEMM'd so far
    for (int k = 1; k < K; ++k) {
        const unsigned short* cur  = B[(k - 1) % 5];
        const unsigned short* prev = (k >= 2) ? B[(k - 2) % 5] : nullptr;
        unsigned short*       nxt  = B[k % 5];
        prop_kernel<<<pb, 256, 0, stream>>>(cur, prev, edges, row_ptr, nxt, N);
        if (k % 4 == 3) {
            int c0 = done;   // first order of chunk
            mega_gemm_kernel<<<gb64, 512, 0, stream>>>(
                B[(c0 + 0) % 5], B[(c0 + 1) % 5], B[(c0 + 2) % 5], B[(c0 + 3) % 5],
                W + (size_t)c0 * DD * DD, bias, out, N, 4, done == 0);
            done += 4;
        }
    }
    // tail chunk (orders done..K-1)
    if (done < K) {
        int nord = K - done;
        mega_gemm_kernel<<<gb64, 512, 0, stream>>>(
            B[(done + 0) % 5], B[(done + 1) % 5],
            B[(done + 2) % 5], B[(done + 3) % 5],
            W + (size_t)done * DD * DD, bias, out, N, nord, done == 0);
    }
}